// Round 6
// baseline (549.292 us; speedup 1.0000x reference)
//
#include <hip/hip_runtime.h>

#define NTOK 1024
#define NB   64
#define CD   256
#define NHEAD 8
#define HDIM 32
#define NS 256
#define NBC 16384

typedef __attribute__((ext_vector_type(8))) short short8v;
typedef __attribute__((ext_vector_type(4))) short short4v;
typedef __attribute__((ext_vector_type(4))) float f32x4;

// round-to-nearest-even fp32 -> bf16 (low 16 bits returned)
__device__ __forceinline__ unsigned bfr(float x){
  unsigned u = __float_as_uint(x);
  return (u + 0x7fffu + ((u>>16)&1u)) >> 16;
}
// two-term split: x ~= hi + lo, both bf16
__device__ __forceinline__ void split2(float x, short &h, short &l){
  unsigned hu = bfr(x);
  float hf = __uint_as_float(hu << 16);
  unsigned lu = bfr(x - hf);
  h = (short)hu; l = (short)lu;
}

// ================= Launch 1: conv | qproj | wcvt(Wk,Wo) | trig | semean =================
__global__ __launch_bounds__(256) void k_mid(const float* __restrict__ qf,
                                             const float* __restrict__ srw,
                                             const float* __restrict__ srb, float* __restrict__ xr,
                                             const float* __restrict__ ipw, const float* __restrict__ ipb,
                                             short* __restrict__ Qbh, short* __restrict__ Qbl,
                                             const float* __restrict__ ow,
                                             short* __restrict__ Wih, short* __restrict__ Wil,
                                             short* __restrict__ Woh, short* __restrict__ Wol,
                                             float* __restrict__ t1, float* __restrict__ t2,
                                             float* __restrict__ part){
  __shared__ __align__(16) short smem[16384];   // 32KB
  int bid = blockIdx.x, t = threadIdx.x;
  if (bid < 512){
    // ---- conv 2x2/s2 as MFMA GEMM: 64m x 128n, K'=1024; A from fp32 query, B from fp32 srw ----
    short* Ah = smem;
    short* Al = smem + 2048;
    short* Bh = smem + 4096;
    short* Bl = smem + 8192;
    int mblk = bid >> 1, nblk = bid & 1;
    int m0 = mblk*64, n0 = nblk*128;
    int b = mblk >> 2;
    int pos0 = m0 & 255;
    int wave = t>>6, lane = t&63;
    int wm = wave>>1, wn = wave&1;
    int q = lane>>4, r = lane&15;
    int ra = t>>2, pa = (t&3)*8;
    int posA = pos0 + ra, hs = posA>>4, ws2 = posA&15;
    const f32x4 fz = {0.f,0.f,0.f,0.f};
    f32x4 acc[2][4];
    #pragma unroll
    for (int s=0;s<2;++s)
      #pragma unroll
      for (int tt=0;tt<4;++tt) acc[s][tt] = fz;
    for (int kc=0; kc<32; ++kc){
      int g = kc>>3, cin0 = (kc&7)*32;
      int gh = g>>1, gw = g&1;
      int tok = (2*hs+gh)*32 + 2*ws2 + gw;
      const float* src = qf + (size_t)tok*NBC + b*CD + cin0 + pa;
      float4 fa = *(const float4*)src;
      float4 fb = *(const float4*)(src+4);
      float xs[8] = {fa.x,fa.y,fa.z,fa.w,fb.x,fb.y,fb.z,fb.w};
      short8v hh, ll;
      #pragma unroll
      for (int i=0;i<8;++i){ short a0,b0; split2(xs[i],a0,b0); hh[i]=a0; ll[i]=b0; }
      *(short8v*)(Ah + ra*32 + pa) = hh;
      *(short8v*)(Al + ra*32 + pa) = ll;
      #pragma unroll
      for (int rep=0; rep<2; ++rep){
        int rr = ra + rep*64;
        const float* wsrc = srw + (size_t)(n0+rr)*1024 + (size_t)(cin0+pa)*4 + g;
        short8v wh8, wl8;
        #pragma unroll
        for (int i=0;i<8;++i){ short a0,b0; split2(wsrc[i*4],a0,b0); wh8[i]=a0; wl8[i]=b0; }
        *(short8v*)(Bh + rr*32 + pa) = wh8;
        *(short8v*)(Bl + rr*32 + pa) = wl8;
      }
      __syncthreads();
      short8v ah[2], al[2];
      #pragma unroll
      for (int s=0;s<2;++s){
        int row = wm*32 + s*16 + r;
        ah[s] = *(const short8v*)(Ah + row*32 + q*8);
        al[s] = *(const short8v*)(Al + row*32 + q*8);
      }
      #pragma unroll
      for (int tt=0;tt<4;++tt){
        int brow = wn*64 + tt*16 + r;
        short8v bh = *(const short8v*)(Bh + brow*32 + q*8);
        short8v bl = *(const short8v*)(Bl + brow*32 + q*8);
        #pragma unroll
        for (int s=0;s<2;++s){
          acc[s][tt] = __builtin_amdgcn_mfma_f32_16x16x32_bf16(ah[s], bh, acc[s][tt], 0,0,0);
          acc[s][tt] = __builtin_amdgcn_mfma_f32_16x16x32_bf16(ah[s], bl, acc[s][tt], 0,0,0);
          acc[s][tt] = __builtin_amdgcn_mfma_f32_16x16x32_bf16(al[s], bh, acc[s][tt], 0,0,0);
        }
      }
      __syncthreads();
    }
    #pragma unroll
    for (int s=0;s<2;++s){
      #pragma unroll
      for (int tt=0;tt<4;++tt){
        int c = n0 + wn*64 + tt*16 + r;
        float bias = srb[c];
        #pragma unroll
        for (int i=0;i<4;++i){
          int m = m0 + wm*32 + s*16 + q*4 + i;
          xr[m*CD + c] = acc[s][tt][i] + bias;
        }
      }
    }
  } else if (bid < 1536){
    // ---- Q proj MFMA: 128x128; A from fp32 query, B from fp32 ipw rows 0..255; swizzled staging;
    //      epilogue: relu,*sc,split2 -> LDS transpose -> head-major stores [h][m][32] ----
    short* Ah = smem;
    short* Al = smem + 4096;
    short* Bh = smem + 8192;
    short* Bl = smem + 12288;
    int qb_ = bid - 512;
    int mblk = qb_ >> 1, nblk = qb_ & 1;
    int m0 = mblk*128, n0 = nblk*128;
    int wave = t>>6, lane = t&63;
    int wm = wave>>1, wn = wave&1;
    int q = lane>>4, r = lane&15;
    int cr = t>>2, cp = (t&3)*8;
    int cpS = (((t&3) ^ ((cr>>1)&3)))*8;       // swizzled staging-write chunk
    int sw8 = ((r>>1)&3)*8;                    // lane-constant fragment-read swizzle
    const f32x4 fz = {0.f,0.f,0.f,0.f};
    f32x4 acc[4][4];
    #pragma unroll
    for (int s=0;s<4;++s)
      #pragma unroll
      for (int tt=0;tt<4;++tt) acc[s][tt] = fz;
    for (int kc=0; kc<8; ++kc){
      int ko = kc*32;
      #pragma unroll
      for (int rep=0; rep<2; ++rep){
        int rr = cr + rep*64;
        int m = m0 + rr;
        const float* src = qf + (size_t)(m & 1023)*NBC + (m >> 10)*CD + ko + cp;
        float4 fa = *(const float4*)src;
        float4 fb = *(const float4*)(src+4);
        float xs[8] = {fa.x,fa.y,fa.z,fa.w,fb.x,fb.y,fb.z,fb.w};
        short8v hh, ll;
        #pragma unroll
        for (int i=0;i<8;++i){ short a0,b0; split2(xs[i],a0,b0); hh[i]=a0; ll[i]=b0; }
        *(short8v*)(Ah + rr*32 + cpS) = hh;
        *(short8v*)(Al + rr*32 + cpS) = ll;
        const float* wsrc = ipw + (size_t)(n0+rr)*CD + ko + cp;
        float4 wa = *(const float4*)wsrc;
        float4 wb = *(const float4*)(wsrc+4);
        float wsv[8] = {wa.x,wa.y,wa.z,wa.w,wb.x,wb.y,wb.z,wb.w};
        short8v wh8, wl8;
        #pragma unroll
        for (int i=0;i<8;++i){ short a0,b0; split2(wsv[i],a0,b0); wh8[i]=a0; wl8[i]=b0; }
        *(short8v*)(Bh + rr*32 + cpS) = wh8;
        *(short8v*)(Bl + rr*32 + cpS) = wl8;
      }
      __syncthreads();
      short8v ah[4], al[4];
      #pragma unroll
      for (int s=0;s<4;++s){
        int row = wm*64 + s*16 + r;
        ah[s] = *(const short8v*)(Ah + row*32 + ((q*8)^sw8));
        al[s] = *(const short8v*)(Al + row*32 + ((q*8)^sw8));
      }
      #pragma unroll
      for (int tt=0;tt<4;++tt){
        int brow = wn*64 + tt*16 + r;
        short8v bh = *(const short8v*)(Bh + brow*32 + ((q*8)^sw8));
        short8v bl = *(const short8v*)(Bl + brow*32 + ((q*8)^sw8));
        #pragma unroll
        for (int s=0;s<4;++s){
          acc[s][tt] = __builtin_amdgcn_mfma_f32_16x16x32_bf16(ah[s], bh, acc[s][tt], 0,0,0);
          acc[s][tt] = __builtin_amdgcn_mfma_f32_16x16x32_bf16(ah[s], bl, acc[s][tt], 0,0,0);
          acc[s][tt] = __builtin_amdgcn_mfma_f32_16x16x32_bf16(al[s], bh, acc[s][tt], 0,0,0);
        }
      }
      __syncthreads();
    }
    const float sc = 0.17677669529663687f;
    short* T = smem;   // 128 rows x 128 shorts
    #pragma unroll
    for (int s=0;s<4;++s){
      #pragma unroll
      for (int tt=0;tt<4;++tt){
        int c_loc = wn*64 + tt*16 + r;
        int chunk = c_loc >> 3, cb = c_loc & 7;
        float bias = ipb[n0 + c_loc];
        #pragma unroll
        for (int i=0;i<4;++i){
          int m_loc = wm*64 + s*16 + q*4 + i;
          float val = fmaxf(acc[s][tt][i] + bias, 0.f)*sc;
          unsigned hu = bfr(val);
          T[m_loc*128 + ((chunk ^ (m_loc&7))<<3) + cb] = (short)hu;
          acc[s][tt][i] = val - __uint_as_float(hu<<16);
        }
      }
    }
    __syncthreads();
    {
      int mrl = (lane>>2);
      int ccl = lane&3;
      #pragma unroll
      for (int e=0;e<8;++e){
        int hl = e&3, mg = e>>2;
        int m_loc = wave*32 + mg*16 + mrl;
        int cc16 = hl*4 + ccl;
        short8v v = *(const short8v*)(T + m_loc*128 + ((cc16 ^ (m_loc&7))<<3));
        *(short8v*)(Qbh + ((size_t)((n0>>5)+hl))*2097152 + (size_t)(m0+m_loc)*32 + ccl*8) = v;
      }
    }
    __syncthreads();
    #pragma unroll
    for (int s=0;s<4;++s){
      #pragma unroll
      for (int tt=0;tt<4;++tt){
        int c_loc = wn*64 + tt*16 + r;
        int chunk = c_loc >> 3, cb = c_loc & 7;
        #pragma unroll
        for (int i=0;i<4;++i){
          int m_loc = wm*64 + s*16 + q*4 + i;
          T[m_loc*128 + ((chunk ^ (m_loc&7))<<3) + cb] = (short)bfr(acc[s][tt][i]);
        }
      }
    }
    __syncthreads();
    {
      int mrl = (lane>>2);
      int ccl = lane&3;
      #pragma unroll
      for (int e=0;e<8;++e){
        int hl = e&3, mg = e>>2;
        int m_loc = wave*32 + mg*16 + mrl;
        int cc16 = hl*4 + ccl;
        short8v v = *(const short8v*)(T + m_loc*128 + ((cc16 ^ (m_loc&7))<<3));
        *(short8v*)(Qbl + ((size_t)((n0>>5)+hl))*2097152 + (size_t)(m0+m_loc)*32 + ccl*8) = v;
      }
    }
  } else if (bid < 1632){
    // ---- wcvt: Wi rows 256..767 and Wo -> bf16 planes (24576 units of 8) ----
    int u = (bid-1536)*256 + t;
    const float* s; short* dh; short* dl; int dof;
    if (u < 16384){
      int n = 256 + (u >> 5), off = (u & 31)*8;
      s = ipw + n*CD + off;
      dh = Wih; dl = Wil; dof = n*CD + off;
    } else {
      int v = u - 16384;
      int n = v >> 5, off = (v & 31)*8;
      s = ow + n*CD + off;
      dh = Woh; dl = Wol; dof = n*CD + off;
    }
    short8v h, l;
    #pragma unroll
    for (int i=0;i<8;++i){ short a,b; split2(s[i],a,b); h[i]=a; l[i]=b; }
    *(short8v*)(dh + dof) = h;
    *(short8v*)(dl + dof) = l;
  } else if (bid < 1636){
    // ---- trig tables ----
    int n = (bid-1632)*256 + t;
    const float c = 1.57079632679489662f;
    float aa = c * (float)(n >> 5) / 32.0f;
    float bb = c * (float)(n & 31) / 32.0f;
    t1[n*4+0]=cosf(aa); t1[n*4+1]=sinf(aa); t1[n*4+2]=cosf(bb); t1[n*4+3]=sinf(bb);
    if (n < 256){
      float a2 = c * (float)(n >> 4) / 16.0f;
      float b2 = c * (float)(n & 15) / 16.0f;
      t2[n*4+0]=cosf(a2); t2[n*4+1]=sinf(a2); t2[n*4+2]=cosf(b2); t2[n*4+3]=sinf(b2);
    }
  } else {
    // ---- SE partial mean over tokens of raw fp32 query ----
    int vb_ = bid - 1636;
    int b = vb_ >> 2, qr = vb_ & 3;
    const float* qp = qf + (qr*256)*NBC + b*CD + t;
    float s0=0.f,s1=0.f,s2=0.f,s3=0.f;
    for (int n=0;n<256;n+=4){
      s0 += qp[(n  )*NBC];
      s1 += qp[(n+1)*NBC];
      s2 += qp[(n+2)*NBC];
      s3 += qp[(n+3)*NBC];
    }
    part[vb_*256 + t] = (s0+s1)+(s2+s3);
  }
}

// ================= Launch 2: K/V proj with fused LayerNorm (A from xr fp32) =================
__global__ __launch_bounds__(256) void k_kvproj(const float* __restrict__ xr, const float* __restrict__ lng,
                                                const float* __restrict__ lnb,
                                                const short* __restrict__ Wkh, const short* __restrict__ Wkl,
                                                const float* __restrict__ ipb, float* __restrict__ kb,
                                                float* __restrict__ vb){
  __shared__ __align__(16) short Ah[128*32];
  __shared__ __align__(16) short Al[128*32];
  __shared__ __align__(16) short Bh[128*32];
  __shared__ __align__(16) short Bl[128*32];
  __shared__ float mu_s[128];
  __shared__ float inv_s[128];
  int mblk = blockIdx.x >> 2, nblk = blockIdx.x & 3;
  int m0 = mblk*128, n0 = nblk*128;
  int t = threadIdx.x, wave = t>>6, lane = t&63;
  int wm = wave>>1, wn = wave&1;
  int q = lane>>4, r = lane&15;
  int cr = t>>2, cp = (t&3)*8;
  // ---- LN stats prepass: each wave one row at a time, identical math to old k_ln ----
  for (int rr8=0; rr8<32; ++rr8){
    int rr = rr8*4 + wave;
    float4 v = ((const float4*)(xr + (size_t)(m0+rr)*CD))[lane];
    float s = (v.x+v.y)+(v.z+v.w);
    #pragma unroll
    for (int off=1; off<64; off<<=1) s += __shfl_xor(s, off, 64);
    float mu = s * (1.0f/256.0f);
    float dx=v.x-mu, dy=v.y-mu, dz=v.z-mu, dw=v.w-mu;
    float s2 = (dx*dx+dy*dy)+(dz*dz+dw*dw);
    #pragma unroll
    for (int off=1; off<64; off<<=1) s2 += __shfl_xor(s2, off, 64);
    float inv = 1.0f / sqrtf(s2*(1.0f/256.0f) + 1e-5f);
    if (lane==0){ mu_s[rr]=mu; inv_s[rr]=inv; }
  }
  __syncthreads();
  const f32x4 fz = {0.f,0.f,0.f,0.f};
  f32x4 acc[4][4];
  #pragma unroll
  for (int s=0;s<4;++s)
    #pragma unroll
    for (int tt=0;tt<4;++tt) acc[s][tt] = fz;
  for (int kc=0; kc<8; ++kc){
    int ko = kc*32;
    #pragma unroll
    for (int rep=0; rep<2; ++rep){
      int rr = cr + rep*64;
      const float* src = xr + (size_t)(m0+rr)*CD + ko + cp;
      float4 fa = *(const float4*)src;
      float4 fb = *(const float4*)(src+4);
      float xs[8] = {fa.x,fa.y,fa.z,fa.w,fb.x,fb.y,fb.z,fb.w};
      float4 g0 = *(const float4*)(lng + ko + cp);
      float4 g1 = *(const float4*)(lng + ko + cp + 4);
      float4 b0 = *(const float4*)(lnb + ko + cp);
      float4 b1 = *(const float4*)(lnb + ko + cp + 4);
      float gv[8] = {g0.x,g0.y,g0.z,g0.w,g1.x,g1.y,g1.z,g1.w};
      float bv[8] = {b0.x,b0.y,b0.z,b0.w,b1.x,b1.y,b1.z,b1.w};
      float mu = mu_s[rr], inv = inv_s[rr];
      short8v hh, ll;
      #pragma unroll
      for (int i=0;i<8;++i){
        short a0,bq; split2(((xs[i]-mu)*inv)*gv[i] + bv[i], a0,bq);
        hh[i]=a0; ll[i]=bq;
      }
      *(short8v*)(Ah + rr*32 + cp) = hh;
      *(short8v*)(Al + rr*32 + cp) = ll;
      int gb = (n0 + rr)*CD + ko + cp;
      *(short8v*)(Bh + rr*32 + cp) = *(const short8v*)(Wkh + gb);
      *(short8v*)(Bl + rr*32 + cp) = *(const short8v*)(Wkl + gb);
    }
    __syncthreads();
    short8v ah[4], al[4];
    #pragma unroll
    for (int s=0;s<4;++s){
      int row = wm*64 + s*16 + r;
      ah[s] = *(const short8v*)(Ah + row*32 + q*8);
      al[s] = *(const short8v*)(Al + row*32 + q*8);
    }
    #pragma unroll
    for (int tt=0;tt<4;++tt){
      int brow = wn*64 + tt*16 + r;
      short8v bh = *(const short8v*)(Bh + brow*32 + q*8);
      short8v bl = *(const short8v*)(Bl + brow*32 + q*8);
      #pragma unroll
      for (int s=0;s<4;++s){
        acc[s][tt] = __builtin_amdgcn_mfma_f32_16x16x32_bf16(ah[s], bh, acc[s][tt], 0,0,0);
        acc[s][tt] = __builtin_amdgcn_mfma_f32_16x16x32_bf16(ah[s], bl, acc[s][tt], 0,0,0);
        acc[s][tt] = __builtin_amdgcn_mfma_f32_16x16x32_bf16(al[s], bh, acc[s][tt], 0,0,0);
      }
    }
    __syncthreads();
  }
  #pragma unroll
  for (int s=0;s<4;++s){
    #pragma unroll
    for (int tt=0;tt<4;++tt){
      int c = n0 + wn*64 + tt*16 + r;       // 0..511
      float bias = ipb[256 + c];
      #pragma unroll
      for (int i=0;i<4;++i){
        int m = m0 + wm*64 + s*16 + q*4 + i;
        float v = acc[s][tt][i] + bias;
        if (c < 256) kb[m*CD + c] = fmaxf(v, 0.f);
        else         vb[m*CD + (c-256)] = v;
      }
    }
  }
}

// ================= Launch 3: kv+attn fused per (b,h) | semlp =================
__global__ __launch_bounds__(256) void k_kvattn(const float* __restrict__ kb, const float* __restrict__ vbuf,
                                                const float* __restrict__ t2,
                                                const short* __restrict__ Qbh, const short* __restrict__ Qbl,
                                                const float* __restrict__ t1,
                                                short* __restrict__ Ath, short* __restrict__ Atl,
                                                const float* __restrict__ part, const float* __restrict__ w1,
                                                const float* __restrict__ w2, float* __restrict__ se){
  __shared__ __align__(16) char arena[51200];
  int t = threadIdx.x;
  if (blockIdx.x >= 512){
    // ---- SE MLP ----
    float* sm = (float*)arena;
    float* s1s = sm + 256;
    int b = blockIdx.x - 512;
    float s = (part[(b*4+0)*256+t]+part[(b*4+1)*256+t])+(part[(b*4+2)*256+t]+part[(b*4+3)*256+t]);
    sm[t] = s*(1.0f/1024.0f);
    __syncthreads();
    if (t < 128){
      float a = 0.f;
      const float* wr = w1 + t*256;
      for (int c=0;c<256;c+=4){
        float4 wf = *(const float4*)(wr+c);
        a += sm[c]*wf.x + sm[c+1]*wf.y + sm[c+2]*wf.z + sm[c+3]*wf.w;
      }
      s1s[t] = fmaxf(a, 0.f);
    }
    __syncthreads();
    float a = 0.f;
    const float* wr2 = w2 + t*128;
    for (int c=0;c<128;c+=4){
      float4 wf = *(const float4*)(wr2+c);
      a += s1s[c]*wf.x + s1s[c+1]*wf.y + s1s[c+2]*wf.z + s1s[c+3]*wf.w;
    }
    se[b*256+t] = 1.0f/(1.0f+expf(-a));
    return;
  }
  short* Bh = (short*)arena;                 // 144*32
  short* Bl = (short*)(arena + 9216);
  short* Ah = (short*)(arena + 18432);       // 256*32
  short* Al = (short*)(arena + 34816);
  int bh = blockIdx.x, b = bh>>3, h = bh&7;
  int lane = t&63, wave = t>>6;
  int q = lane>>4, r = lane&15;
  // ---- phase 1: kv (t2-weighted K^T V outer products) straight into LDS B-planes ----
  {
    int jq = t >> 5, m = t & 31;
    float acc[4][4];
    #pragma unroll
    for (int p=0;p<4;++p){ acc[p][0]=0.f; acc[p][1]=0.f; acc[p][2]=0.f; acc[p][3]=0.f; }
    const float* kbase = kb + h*HDIM + jq*4;
    const float* vbase = vbuf + h*HDIM + m;
    for (int n=0;n<256;++n){
      int ro = (b*NS + n)*CD;
      float4 k4 = *(const float4*)(kbase + ro);
      float vv = vbase[ro];
      float4 tt = *(const float4*)(t2 + n*4);
      float tv[4] = {tt.x, tt.y, tt.z, tt.w};
      float kk[4] = {k4.x, k4.y, k4.z, k4.w};
      #pragma unroll
      for (int p=0;p<4;++p){
        float tp = tv[p]*vv;
        #pragma unroll
        for (int jj=0;jj<4;++jj) acc[p][jj] += tp*kk[jj];
      }
    }
    #pragma unroll
    for (int p=0;p<4;++p){
      short4v h4, l4;
      #pragma unroll
      for (int jj=0;jj<4;++jj){ short a,bq; split2(acc[p][jj],a,bq); h4[jj]=a; l4[jj]=bq; }
      *(short4v*)(Bh + (p*32+m)*32 + jq*4) = h4;
      *(short4v*)(Bl + (p*32+m)*32 + jq*4) = l4;
    }
    if (t < 128){
      int p = t >> 5, j = t & 31;
      float s=0.f;
      const float* kp = kb + h*HDIM + j;
      for (int n=0;n<256;++n) s += t2[n*4+p]*kp[(b*NS+n)*CD];
      short a,bq; split2(s,a,bq);
      Bh[(128+p)*32 + j] = a;
      Bl[(128+p)*32 + j] = bq;
    } else {
      int idx = t - 128;       // zero pad rows 132..143 (384 shorts per plane)
      #pragma unroll
      for (int ii=0;ii<3;++ii){
        Bh[4224 + idx*3 + ii] = 0;
        Bl[4224 + idx*3 + ii] = 0;
      }
    }
  }
  __syncthreads();
  // ---- phase 2: attn GEMM (A = Q head planes, B = LDS planes) ----
  short8v bf_h[9], bf_l[9];
  #pragma unroll
  for (int nt=0; nt<9; ++nt){
    int row = nt*16 + r;
    bf_h[nt] = *(const short8v*)(Bh + row*32 + q*8);
    bf_l[nt] = *(const short8v*)(Bl + row*32 + q*8);
  }
  const short* qh_base = Qbh + ((size_t)h*65536 + (size_t)b*1024)*32;
  const short* ql_base = Qbl + ((size_t)h*65536 + (size_t)b*1024)*32;
  const f32x4 fz = {0.f,0.f,0.f,0.f};
  for (int u=0; u<4; ++u){
    __syncthreads();
    {
      const short8v* sh = (const short8v*)(qh_base + (u*256 + t)*32);
      const short8v* sl = (const short8v*)(ql_base + (u*256 + t)*32);
      short8v* dh = (short8v*)(Ah + t*32);
      short8v* dl = (short8v*)(Al + t*32);
      #pragma unroll
      for (int i=0;i<4;++i){ dh[i]=sh[i]; dl[i]=sl[i]; }
    }
    __syncthreads();
    #pragma unroll
    for (int mi=0; mi<4; ++mi){
      int mt = wave*4 + mi;
      short8v ah = *(const short8v*)(Ah + (mt*16 + r)*32 + q*8);
      short8v al = *(const short8v*)(Al + (mt*16 + r)*32 + q*8);
      f32x4 acc[9];
      #pragma unroll
      for (int nt=0;nt<9;++nt) acc[nt]=fz;
      #pragma unroll
      for (int nt=0;nt<9;++nt){
        acc[nt] = __builtin_amdgcn_mfma_f32_16x16x32_bf16(ah, bf_h[nt], acc[nt],0,0,0);
        acc[nt] = __builtin_amdgcn_mfma_f32_16x16x32_bf16(ah, bf_l[nt], acc[nt],0,0,0);
        acc[nt] = __builtin_amdgcn_mfma_f32_16x16x32_bf16(al, bf_h[nt], acc[nt],0,0,0);
      }
      int nbase = u*256 + mt*16 + q*4;
      int src = lane & 48;
      #pragma unroll
      for (int i=0;i<4;++i){
        int n = nbase + i;
        float4 tv = *(const float4*)(t1 + n*4);
        float dp0 = __shfl(acc[8][i], src+0, 64);
        float dp1 = __shfl(acc[8][i], src+1, 64);
        float dp2 = __shfl(acc[8][i], src+2, 64);
        float dp3 = __shfl(acc[8][i], src+3, 64);
        float den = tv.x*dp0 + tv.y*dp1 + tv.z*dp2 + tv.w*dp3;
        float a0 = tv.x*acc[0][i] + tv.y*acc[2][i] + tv.z*acc[4][i] + tv.w*acc[6][i];
        float a1 = tv.x*acc[1][i] + tv.y*acc[3][i] + tv.z*acc[5][i] + tv.w*acc[7][i];
        float sgn = (den>0.f) ? 1.f : ((den<0.f)? -1.f : 0.f);
        float ad = fminf(fmaxf(fabsf(den), 1e-4f), 1e4f);
        float inv = (den != 0.f) ? 1.0f/(ad*sgn) : 0.f;
        float o0 = a0*inv, o1 = a1*inv;
        int mrow = b*NTOK + n;
        short h0,l0,h1,l1;
        split2(o0,h0,l0); split2(o1,h1,l1);
        Ath[mrow*CD + h*HDIM + r]      = h0;
        Atl[mrow*CD + h*HDIM + r]      = l0;
        Ath[mrow*CD + h*HDIM + 16 + r] = h1;
        Atl[mrow*CD + h*HDIM + 16 + r] = l1;
      }
    }
  }
}

// ================= Launch 4: out proj =================
__global__ __launch_bounds__(256) void k_outproj(const short* __restrict__ Ath, const short* __restrict__ Atl,
                                                 const short* __restrict__ Woh, const short* __restrict__ Wol,
                                                 const float* __restrict__ obv, const float* __restrict__ se,
                                                 float* __restrict__ dout){
  __shared__ __align__(16) short Ah[128*32];
  __shared__ __align__(16) short Al[128*32];
  __shared__ __align__(16) short Bh[128*32];
  __shared__ __align__(16) short Bl[128*32];
  int mblk = blockIdx.x >> 1, nblk = blockIdx.x & 1;
  int m0 = mblk*128, n0 = nblk*128;
  int t = threadIdx.x, wave = t>>6, lane = t&63;
  int wm = wave>>1, wn = wave&1;
  int q = lane>>4, r = lane&15;
  int cr = t>>2, cp = (t&3)*8;
  const f32x4 fz = {0.f,0.f,0.f,0.f};
  f32x4 acc[4][4];
  #pragma unroll
  for (int s=0;s<4;++s)
    #pragma unroll
    for (int tt=0;tt<4;++tt) acc[s][tt] = fz;
  for (int kc=0; kc<8; ++kc){
    int ko = kc*32;
    #pragma unroll
    for (int rep=0; rep<2; ++rep){
      int rr = cr + rep*64;
      int ga = (m0 + rr)*CD + ko + cp;
      *(short8v*)(Ah + rr*32 + cp) = *(const short8v*)(Ath + ga);
      *(short8v*)(Al + rr*32 + cp) = *(const short8v*)(Atl + ga);
      int gb = (n0 + rr)*CD + ko + cp;
      *(short8v*)(Bh + rr*32 + cp) = *(const short8v*)(Woh + gb);
      *(short8v*)(Bl + rr*32 + cp) = *(const short8v*)(Wol + gb);
    }
    __syncthreads();
    short8v ah[4], al[4];
    #pragma unroll
    for (int s=0;s<4;++s){
      int row = wm*64 + s*16 + r;
      ah[s] = *(const short8v*)(Ah + row*32 + q*8);
      al[s] = *(const short8v*)(Al + row*32 + q*8);
    }
    #pragma unroll
    for (int tt=0;tt<4;++tt){
      int brow = wn*64 + tt*16 + r;
      short8v bh = *(const short8v*)(Bh + brow*32 + q*8);
      short8v bl = *(const short8v*)(Bl + brow*32 + q*8);
      #pragma unroll
      for (int s=0;s<4;++s){
        acc[s][tt] = __builtin_amdgcn_mfma_f32_16x16x32_bf16(ah[s], bh, acc[s][tt], 0,0,0);
        acc[s][tt] = __builtin_amdgcn_mfma_f32_16x16x32_bf16(ah[s], bl, acc[s][tt], 0,0,0);
        acc[s][tt] = __builtin_amdgcn_mfma_f32_16x16x32_bf16(al[s], bh, acc[s][tt], 0,0,0);
      }
    }
    __syncthreads();
  }
  #pragma unroll
  for (int s=0;s<4;++s){
    #pragma unroll
    for (int tt=0;tt<4;++tt){
      int c = n0 + wn*64 + tt*16 + r;
      float bias = obv[c];
      #pragma unroll
      for (int i=0;i<4;++i){
        int m = m0 + wm*64 + s*16 + q*4 + i;
        int bb = m >> 10, ntok = m & 1023;
        float sev = se[bb*CD + c];
        dout[(ntok*NB + bb)*CD + c] = (acc[s][tt][i] + bias)*sev;
      }
    }
  }
}

extern "C" void kernel_launch(void* const* d_in, const int* in_sizes, int n_in,
                              void* d_out, int out_size, void* d_ws, size_t ws_size,
                              hipStream_t stream) {
  const float* query = (const float*)d_in[0];
  const float* ipw = (const float*)d_in[5];
  const float* ipb = (const float*)d_in[6];
  const float* srw = (const float*)d_in[7];
  const float* srb = (const float*)d_in[8];
  const float* ng  = (const float*)d_in[9];
  const float* nbb = (const float*)d_in[10];
  const float* ow  = (const float*)d_in[11];
  const float* obv = (const float*)d_in[12];
  const float* sw1 = (const float*)d_in[13];
  const float* sw2 = (const float*)d_in[14];
  float* dout = (float*)d_out;
  float* ws = (float*)d_ws;

  // ---- workspace layout (float offsets) ----
  short* Qbh  = (short*)ws;                // q head planes [h][m][32] [L1 qproj -> L3 attn]
  short* Qbl  = (short*)(ws + 8388608);
  float* R1   = ws + 16777216;             // multi-use region (16,777,216 f)
  float* kb   = R1;                        //  4,194,304 f  [L2 -> L3]
  float* vb   = R1 + 4194304;              //  4,194,304 f  [L2 -> L3]
  short* Ath  = (short*)(R1 + 8388608);    //  At hi plane [L3 -> L4] (no overlap with kb/vb)
  short* Atl  = (short*)(ws + 33554432);   //  At lo plane (over xr, dead after L2)
  float* xr   = ws + 33554432;             //  4,194,304 f  [L1 conv -> L2]
  float* part = ws + 44302336;             //     65,536 f  [L1 semean -> L3 semlp]
  float* se   = ws + 44367872;             //     16,384 f  [L3 semlp -> L4]
  float* t1   = ws + 44384256;             //      4,096 f
  float* t2   = ws + 44388352;             //      1,024 f
  short* Wih  = (short*)(ws + 44389376);   // 768x256 (rows 256..767 filled by L1 wcvt)
  short* Wil  = (short*)(ws + 44487680);
  short* Woh  = (short*)(ws + 44585984);   // 256x256
  short* Wol  = (short*)(ws + 44618752);   // end ~44.7M f

  // L1: conv(512) | qproj(1024) | wcvt(96) | trig(4) | semean(256)
  k_mid   <<<1892, 256,0,stream>>>(query, srw, srb, xr, ipw, ipb, Qbh, Qbl, ow,
                                   Wih, Wil, Woh, Wol, t1, t2, part);
  // L2: kvproj + fused layernorm
  k_kvproj<<<512,  256,0,stream>>>(xr, ng, nbb, Wih + 256*CD, Wil + 256*CD, ipb, kb, vb);
  // L3: kv+attn fused (512) | semlp(64)
  k_kvattn<<<576,  256,0,stream>>>(kb, vb, t2, Qbh, Qbl, t1, Ath, Atl, part, sw1, sw2, se);
  // L4: out proj
  k_outproj<<<1024,256,0,stream>>>(Ath, Atl, Woh, Wol, obv, se, dout);
}

// Round 7
// 447.926 us; speedup vs baseline: 1.2263x; 1.2263x over previous
//
#include <hip/hip_runtime.h>

#define NTOK 1024
#define NB   64
#define CD   256
#define NHEAD 8
#define HDIM 32
#define NS 256
#define NBC 16384

typedef __attribute__((ext_vector_type(8))) short short8v;
typedef __attribute__((ext_vector_type(4))) short short4v;
typedef __attribute__((ext_vector_type(4))) float f32x4;

// round-to-nearest-even fp32 -> bf16 (low 16 bits returned)
__device__ __forceinline__ unsigned bfr(float x){
  unsigned u = __float_as_uint(x);
  return (u + 0x7fffu + ((u>>16)&1u)) >> 16;
}
// two-term split: x ~= hi + lo, both bf16
__device__ __forceinline__ void split2(float x, short &h, short &l){
  unsigned hu = bfr(x);
  float hf = __uint_as_float(hu << 16);
  unsigned lu = bfr(x - hf);
  h = (short)hu; l = (short)lu;
}

// ================= L0: wcvt | trig | semean =================
__global__ __launch_bounds__(256) void k_pre(const float* __restrict__ ipw, const float* __restrict__ ow,
                                             const float* __restrict__ srw,
                                             short* __restrict__ Wih, short* __restrict__ Wil,
                                             short* __restrict__ Woh, short* __restrict__ Wol,
                                             short* __restrict__ Wsh, short* __restrict__ Wsl,
                                             float* __restrict__ t1, float* __restrict__ t2,
                                             const float* __restrict__ query, float* __restrict__ part){
  int bid = blockIdx.x, t = threadIdx.x;
  if (bid < 256){
    // ---- weights -> bf16 hi/lo planes ----
    int u = bid*256 + t;
    float xs[8];
    short* dh; short* dl; int dof;
    if (u < 24576){
      int n = u >> 5, off = (u & 31)*8;
      const float* s = ipw + n*CD + off;
      #pragma unroll
      for (int i=0;i<8;++i) xs[i] = s[i];
      dh = Wih; dl = Wil; dof = n*CD + off;
    } else if (u < 32768){
      int v = u - 24576;
      int n = v >> 5, off = (v & 31)*8;
      const float* s = ow + n*CD + off;
      #pragma unroll
      for (int i=0;i<8;++i) xs[i] = s[i];
      dh = Woh; dl = Wol; dof = n*CD + off;
    } else {
      int v = u - 32768;
      int n = v >> 7, koff = (v & 127)*8;
      int g = koff >> 8, cin0 = koff & 255;
      #pragma unroll
      for (int i=0;i<8;++i) xs[i] = srw[n*1024 + (cin0+i)*4 + g];
      dh = Wsh; dl = Wsl; dof = n*1024 + koff;
    }
    short8v h, l;
    #pragma unroll
    for (int i=0;i<8;++i){ short a,b; split2(xs[i],a,b); h[i]=a; l[i]=b; }
    *(short8v*)(dh + dof) = h;
    *(short8v*)(dl + dof) = l;
  } else if (bid < 260){
    // ---- trig tables ----
    int n = (bid-256)*256 + t;
    const float c = 1.57079632679489662f;
    float aa = c * (float)(n >> 5) / 32.0f;
    float bb = c * (float)(n & 31) / 32.0f;
    t1[n*4+0]=cosf(aa); t1[n*4+1]=sinf(aa); t1[n*4+2]=cosf(bb); t1[n*4+3]=sinf(bb);
    if (n < 256){
      float a2 = c * (float)(n >> 4) / 16.0f;
      float b2 = c * (float)(n & 15) / 16.0f;
      t2[n*4+0]=cosf(a2); t2[n*4+1]=sinf(a2); t2[n*4+2]=cosf(b2); t2[n*4+3]=sinf(b2);
    }
  } else {
    // ---- SE partial mean over tokens of raw fp32 query ----
    int vb_ = bid - 260;
    int b = vb_ >> 2, qr = vb_ & 3;
    const float* qp = query + (qr*256)*NBC + b*CD + t;
    float s0=0.f,s1=0.f,s2=0.f,s3=0.f;
    for (int n=0;n<256;n+=4){
      s0 += qp[(n  )*NBC];
      s1 += qp[(n+1)*NBC];
      s2 += qp[(n+2)*NBC];
      s3 += qp[(n+3)*NBC];
    }
    part[vb_*256 + t] = (s0+s1)+(s2+s3);
  }
}

// ================= L1: conv | qproj | semlp =================
__global__ __launch_bounds__(256) void k_mid(const float* __restrict__ qf,
                                             const short* __restrict__ Wsh, const short* __restrict__ Wsl,
                                             const float* __restrict__ srb, float* __restrict__ xr,
                                             const short* __restrict__ Wih, const short* __restrict__ Wil,
                                             const float* __restrict__ ipb,
                                             short* __restrict__ Qbh, short* __restrict__ Qbl,
                                             const float* __restrict__ part, const float* __restrict__ w1,
                                             const float* __restrict__ w2, float* __restrict__ se){
  __shared__ __align__(16) short smem[16384];   // 32KB
  int bid = blockIdx.x, t = threadIdx.x;
  if (bid < 512){
    // ---- conv 2x2/s2 as MFMA GEMM: 64m x 128n, K'=1024; A from fp32 query + split2 ----
    short* Ah = smem;
    short* Al = smem + 2048;
    short* Bh = smem + 4096;
    short* Bl = smem + 8192;
    int mblk = bid >> 1, nblk = bid & 1;
    int m0 = mblk*64, n0 = nblk*128;
    int b = mblk >> 2;
    int pos0 = m0 & 255;
    int wave = t>>6, lane = t&63;
    int wm = wave>>1, wn = wave&1;
    int q = lane>>4, r = lane&15;
    int ra = t>>2, pa = (t&3)*8;
    int posA = pos0 + ra, hs = posA>>4, ws2 = posA&15;
    const f32x4 fz = {0.f,0.f,0.f,0.f};
    f32x4 acc[2][4];
    #pragma unroll
    for (int s=0;s<2;++s)
      #pragma unroll
      for (int tt=0;tt<4;++tt) acc[s][tt] = fz;
    for (int kc=0; kc<32; ++kc){
      int g = kc>>3, cin0 = (kc&7)*32;
      int gh = g>>1, gw = g&1;
      int tok = (2*hs+gh)*32 + 2*ws2 + gw;
      const float* src = qf + (size_t)tok*NBC + b*CD + cin0 + pa;
      float4 fa = *(const float4*)src;
      float4 fb = *(const float4*)(src+4);
      float xs[8] = {fa.x,fa.y,fa.z,fa.w,fb.x,fb.y,fb.z,fb.w};
      short8v hh, ll;
      #pragma unroll
      for (int i=0;i<8;++i){ short a0,b0; split2(xs[i],a0,b0); hh[i]=a0; ll[i]=b0; }
      *(short8v*)(Ah + ra*32 + pa) = hh;
      *(short8v*)(Al + ra*32 + pa) = ll;
      int ko = kc*32;
      #pragma unroll
      for (int rep=0; rep<2; ++rep){
        int rr = ra + rep*64;
        int gb = (n0 + rr)*1024 + ko + pa;
        *(short8v*)(Bh + rr*32 + pa) = *(const short8v*)(Wsh + gb);
        *(short8v*)(Bl + rr*32 + pa) = *(const short8v*)(Wsl + gb);
      }
      __syncthreads();
      short8v ah[2], al[2];
      #pragma unroll
      for (int s=0;s<2;++s){
        int row = wm*32 + s*16 + r;
        ah[s] = *(const short8v*)(Ah + row*32 + q*8);
        al[s] = *(const short8v*)(Al + row*32 + q*8);
      }
      #pragma unroll
      for (int tt=0;tt<4;++tt){
        int brow = wn*64 + tt*16 + r;
        short8v bh = *(const short8v*)(Bh + brow*32 + q*8);
        short8v bl = *(const short8v*)(Bl + brow*32 + q*8);
        #pragma unroll
        for (int s=0;s<2;++s){
          acc[s][tt] = __builtin_amdgcn_mfma_f32_16x16x32_bf16(ah[s], bh, acc[s][tt], 0,0,0);
          acc[s][tt] = __builtin_amdgcn_mfma_f32_16x16x32_bf16(ah[s], bl, acc[s][tt], 0,0,0);
          acc[s][tt] = __builtin_amdgcn_mfma_f32_16x16x32_bf16(al[s], bh, acc[s][tt], 0,0,0);
        }
      }
      __syncthreads();
    }
    #pragma unroll
    for (int s=0;s<2;++s){
      #pragma unroll
      for (int tt=0;tt<4;++tt){
        int c = n0 + wn*64 + tt*16 + r;
        float bias = srb[c];
        #pragma unroll
        for (int i=0;i<4;++i){
          int m = m0 + wm*32 + s*16 + q*4 + i;
          xr[m*CD + c] = acc[s][tt][i] + bias;
        }
      }
    }
  } else if (bid < 1536){
    // ---- Q proj MFMA: 128x128; A from fp32 query + split2; B from bf16 planes; swizzled staging;
    //      epilogue: relu,*sc,split2 -> LDS transpose -> head-major stores [h][m][32] ----
    short* Ah = smem;
    short* Al = smem + 4096;
    short* Bh = smem + 8192;
    short* Bl = smem + 12288;
    int qb_ = bid - 512;
    int mblk = qb_ >> 1, nblk = qb_ & 1;
    int m0 = mblk*128, n0 = nblk*128;
    int wave = t>>6, lane = t&63;
    int wm = wave>>1, wn = wave&1;
    int q = lane>>4, r = lane&15;
    int cr = t>>2, cp = (t&3)*8;
    int cpS = (((t&3) ^ ((cr>>1)&3)))*8;       // swizzled staging-write chunk
    int sw8 = ((r>>1)&3)*8;                    // lane-constant fragment-read swizzle
    const f32x4 fz = {0.f,0.f,0.f,0.f};
    f32x4 acc[4][4];
    #pragma unroll
    for (int s=0;s<4;++s)
      #pragma unroll
      for (int tt=0;tt<4;++tt) acc[s][tt] = fz;
    for (int kc=0; kc<8; ++kc){
      int ko = kc*32;
      #pragma unroll
      for (int rep=0; rep<2; ++rep){
        int rr = cr + rep*64;
        int m = m0 + rr;
        const float* src = qf + (size_t)(m & 1023)*NBC + (m >> 10)*CD + ko + cp;
        float4 fa = *(const float4*)src;
        float4 fb = *(const float4*)(src+4);
        float xs[8] = {fa.x,fa.y,fa.z,fa.w,fb.x,fb.y,fb.z,fb.w};
        short8v hh, ll;
        #pragma unroll
        for (int i=0;i<8;++i){ short a0,b0; split2(xs[i],a0,b0); hh[i]=a0; ll[i]=b0; }
        *(short8v*)(Ah + rr*32 + cpS) = hh;
        *(short8v*)(Al + rr*32 + cpS) = ll;
        int gb = (n0 + rr)*CD + ko + cp;
        *(short8v*)(Bh + rr*32 + cpS) = *(const short8v*)(Wih + gb);
        *(short8v*)(Bl + rr*32 + cpS) = *(const short8v*)(Wil + gb);
      }
      __syncthreads();
      short8v ah[4], al[4];
      #pragma unroll
      for (int s=0;s<4;++s){
        int row = wm*64 + s*16 + r;
        ah[s] = *(const short8v*)(Ah + row*32 + ((q*8)^sw8));
        al[s] = *(const short8v*)(Al + row*32 + ((q*8)^sw8));
      }
      #pragma unroll
      for (int tt=0;tt<4;++tt){
        int brow = wn*64 + tt*16 + r;
        short8v bh = *(const short8v*)(Bh + brow*32 + ((q*8)^sw8));
        short8v bl = *(const short8v*)(Bl + brow*32 + ((q*8)^sw8));
        #pragma unroll
        for (int s=0;s<4;++s){
          acc[s][tt] = __builtin_amdgcn_mfma_f32_16x16x32_bf16(ah[s], bh, acc[s][tt], 0,0,0);
          acc[s][tt] = __builtin_amdgcn_mfma_f32_16x16x32_bf16(ah[s], bl, acc[s][tt], 0,0,0);
          acc[s][tt] = __builtin_amdgcn_mfma_f32_16x16x32_bf16(al[s], bh, acc[s][tt], 0,0,0);
        }
      }
      __syncthreads();
    }
    const float sc = 0.17677669529663687f;
    short* T = smem;   // 128 rows x 128 shorts
    #pragma unroll
    for (int s=0;s<4;++s){
      #pragma unroll
      for (int tt=0;tt<4;++tt){
        int c_loc = wn*64 + tt*16 + r;
        int chunk = c_loc >> 3, cb = c_loc & 7;
        float bias = ipb[n0 + c_loc];
        #pragma unroll
        for (int i=0;i<4;++i){
          int m_loc = wm*64 + s*16 + q*4 + i;
          float val = fmaxf(acc[s][tt][i] + bias, 0.f)*sc;
          unsigned hu = bfr(val);
          T[m_loc*128 + ((chunk ^ (m_loc&7))<<3) + cb] = (short)hu;
          acc[s][tt][i] = val - __uint_as_float(hu<<16);
        }
      }
    }
    __syncthreads();
    {
      int mrl = (lane>>2);
      int ccl = lane&3;
      #pragma unroll
      for (int e=0;e<8;++e){
        int hl = e&3, mg = e>>2;
        int m_loc = wave*32 + mg*16 + mrl;
        int cc16 = hl*4 + ccl;
        short8v v = *(const short8v*)(T + m_loc*128 + ((cc16 ^ (m_loc&7))<<3));
        *(short8v*)(Qbh + ((size_t)((n0>>5)+hl))*2097152 + (size_t)(m0+m_loc)*32 + ccl*8) = v;
      }
    }
    __syncthreads();
    #pragma unroll
    for (int s=0;s<4;++s){
      #pragma unroll
      for (int tt=0;tt<4;++tt){
        int c_loc = wn*64 + tt*16 + r;
        int chunk = c_loc >> 3, cb = c_loc & 7;
        #pragma unroll
        for (int i=0;i<4;++i){
          int m_loc = wm*64 + s*16 + q*4 + i;
          T[m_loc*128 + ((chunk ^ (m_loc&7))<<3) + cb] = (short)bfr(acc[s][tt][i]);
        }
      }
    }
    __syncthreads();
    {
      int mrl = (lane>>2);
      int ccl = lane&3;
      #pragma unroll
      for (int e=0;e<8;++e){
        int hl = e&3, mg = e>>2;
        int m_loc = wave*32 + mg*16 + mrl;
        int cc16 = hl*4 + ccl;
        short8v v = *(const short8v*)(T + m_loc*128 + ((cc16 ^ (m_loc&7))<<3));
        *(short8v*)(Qbl + ((size_t)((n0>>5)+hl))*2097152 + (size_t)(m0+m_loc)*32 + ccl*8) = v;
      }
    }
  } else {
    // ---- SE MLP ----
    float* sm = (float*)smem;
    float* s1s = sm + 256;
    int b = bid - 1536;
    float s = (part[(b*4+0)*256+t]+part[(b*4+1)*256+t])+(part[(b*4+2)*256+t]+part[(b*4+3)*256+t]);
    sm[t] = s*(1.0f/1024.0f);
    __syncthreads();
    if (t < 128){
      float a = 0.f;
      const float* wr = w1 + t*256;
      for (int c=0;c<256;c+=4){
        float4 wf = *(const float4*)(wr+c);
        a += sm[c]*wf.x + sm[c+1]*wf.y + sm[c+2]*wf.z + sm[c+3]*wf.w;
      }
      s1s[t] = fmaxf(a, 0.f);
    }
    __syncthreads();
    float a = 0.f;
    const float* wr2 = w2 + t*128;
    for (int c=0;c<128;c+=4){
      float4 wf = *(const float4*)(wr2+c);
      a += s1s[c]*wf.x + s1s[c+1]*wf.y + s1s[c+2]*wf.z + s1s[c+3]*wf.w;
    }
    se[b*256+t] = 1.0f/(1.0f+expf(-a));
  }
}

// ================= L2: K/V proj with fused LayerNorm (A from xr fp32) =================
__global__ __launch_bounds__(256) void k_kvproj(const float* __restrict__ xr, const float* __restrict__ lng,
                                                const float* __restrict__ lnb,
                                                const short* __restrict__ Wkh, const short* __restrict__ Wkl,
                                                const float* __restrict__ ipb, float* __restrict__ kb,
                                                float* __restrict__ vb){
  __shared__ __align__(16) short Ah[128*32];
  __shared__ __align__(16) short Al[128*32];
  __shared__ __align__(16) short Bh[128*32];
  __shared__ __align__(16) short Bl[128*32];
  __shared__ float mu_s[128];
  __shared__ float inv_s[128];
  int mblk = blockIdx.x >> 2, nblk = blockIdx.x & 3;
  int m0 = mblk*128, n0 = nblk*128;
  int t = threadIdx.x, wave = t>>6, lane = t&63;
  int wm = wave>>1, wn = wave&1;
  int q = lane>>4, r = lane&15;
  int cr = t>>2, cp = (t&3)*8;
  // ---- LN stats prepass: identical math to the original k_ln ----
  for (int rr8=0; rr8<32; ++rr8){
    int rr = rr8*4 + wave;
    float4 v = ((const float4*)(xr + (size_t)(m0+rr)*CD))[lane];
    float s = (v.x+v.y)+(v.z+v.w);
    #pragma unroll
    for (int off=1; off<64; off<<=1) s += __shfl_xor(s, off, 64);
    float mu = s * (1.0f/256.0f);
    float dx=v.x-mu, dy=v.y-mu, dz=v.z-mu, dw=v.w-mu;
    float s2 = (dx*dx+dy*dy)+(dz*dz+dw*dw);
    #pragma unroll
    for (int off=1; off<64; off<<=1) s2 += __shfl_xor(s2, off, 64);
    float inv = 1.0f / sqrtf(s2*(1.0f/256.0f) + 1e-5f);
    if (lane==0){ mu_s[rr]=mu; inv_s[rr]=inv; }
  }
  __syncthreads();
  const f32x4 fz = {0.f,0.f,0.f,0.f};
  f32x4 acc[4][4];
  #pragma unroll
  for (int s=0;s<4;++s)
    #pragma unroll
    for (int tt=0;tt<4;++tt) acc[s][tt] = fz;
  for (int kc=0; kc<8; ++kc){
    int ko = kc*32;
    #pragma unroll
    for (int rep=0; rep<2; ++rep){
      int rr = cr + rep*64;
      const float* src = xr + (size_t)(m0+rr)*CD + ko + cp;
      float4 fa = *(const float4*)src;
      float4 fb = *(const float4*)(src+4);
      float xs[8] = {fa.x,fa.y,fa.z,fa.w,fb.x,fb.y,fb.z,fb.w};
      float4 g0 = *(const float4*)(lng + ko + cp);
      float4 g1 = *(const float4*)(lng + ko + cp + 4);
      float4 b0 = *(const float4*)(lnb + ko + cp);
      float4 b1 = *(const float4*)(lnb + ko + cp + 4);
      float gv[8] = {g0.x,g0.y,g0.z,g0.w,g1.x,g1.y,g1.z,g1.w};
      float bv[8] = {b0.x,b0.y,b0.z,b0.w,b1.x,b1.y,b1.z,b1.w};
      float mu = mu_s[rr], inv = inv_s[rr];
      short8v hh, ll;
      #pragma unroll
      for (int i=0;i<8;++i){
        short a0,bq; split2(((xs[i]-mu)*inv)*gv[i] + bv[i], a0,bq);
        hh[i]=a0; ll[i]=bq;
      }
      *(short8v*)(Ah + rr*32 + cp) = hh;
      *(short8v*)(Al + rr*32 + cp) = ll;
      int gb = (n0 + rr)*CD + ko + cp;
      *(short8v*)(Bh + rr*32 + cp) = *(const short8v*)(Wkh + gb);
      *(short8v*)(Bl + rr*32 + cp) = *(const short8v*)(Wkl + gb);
    }
    __syncthreads();
    short8v ah[4], al[4];
    #pragma unroll
    for (int s=0;s<4;++s){
      int row = wm*64 + s*16 + r;
      ah[s] = *(const short8v*)(Ah + row*32 + q*8);
      al[s] = *(const short8v*)(Al + row*32 + q*8);
    }
    #pragma unroll
    for (int tt=0;tt<4;++tt){
      int brow = wn*64 + tt*16 + r;
      short8v bh = *(const short8v*)(Bh + brow*32 + q*8);
      short8v bl = *(const short8v*)(Bl + brow*32 + q*8);
      #pragma unroll
      for (int s=0;s<4;++s){
        acc[s][tt] = __builtin_amdgcn_mfma_f32_16x16x32_bf16(ah[s], bh, acc[s][tt], 0,0,0);
        acc[s][tt] = __builtin_amdgcn_mfma_f32_16x16x32_bf16(ah[s], bl, acc[s][tt], 0,0,0);
        acc[s][tt] = __builtin_amdgcn_mfma_f32_16x16x32_bf16(al[s], bh, acc[s][tt], 0,0,0);
      }
    }
    __syncthreads();
  }
  #pragma unroll
  for (int s=0;s<4;++s){
    #pragma unroll
    for (int tt=0;tt<4;++tt){
      int c = n0 + wn*64 + tt*16 + r;       // 0..511
      float bias = ipb[256 + c];
      #pragma unroll
      for (int i=0;i<4;++i){
        int m = m0 + wm*64 + s*16 + q*4 + i;
        float v = acc[s][tt][i] + bias;
        if (c < 256) kb[m*CD + c] = fmaxf(v, 0.f);
        else         vb[m*CD + (c-256)] = v;
      }
    }
  }
}

// ================= L3: kv + attn fused per (b,h) =================
__global__ __launch_bounds__(256) void k_kvattn(const float* __restrict__ kb, const float* __restrict__ vbuf,
                                                const float* __restrict__ t2,
                                                const short* __restrict__ Qbh, const short* __restrict__ Qbl,
                                                const float* __restrict__ t1,
                                                short* __restrict__ Ath, short* __restrict__ Atl){
  __shared__ __align__(16) short Bh[144*32];
  __shared__ __align__(16) short Bl[144*32];
  __shared__ __align__(16) short Ah[256*32];
  __shared__ __align__(16) short Al[256*32];
  int bh = blockIdx.x, b = bh>>3, h = bh&7;
  int t = threadIdx.x, lane = t&63, wave = t>>6;
  int q = lane>>4, r = lane&15;
  // ---- phase 1: kv (t2-weighted K^T V outer products) straight into LDS B-planes ----
  {
    int jq = t >> 5, m = t & 31;
    float acc[4][4];
    #pragma unroll
    for (int p=0;p<4;++p){ acc[p][0]=0.f; acc[p][1]=0.f; acc[p][2]=0.f; acc[p][3]=0.f; }
    const float* kbase = kb + h*HDIM + jq*4;
    const float* vbase = vbuf + h*HDIM + m;
    for (int n=0;n<256;++n){
      int ro = (b*NS + n)*CD;
      float4 k4 = *(const float4*)(kbase + ro);
      float vv = vbase[ro];
      float4 tt = *(const float4*)(t2 + n*4);
      float tv[4] = {tt.x, tt.y, tt.z, tt.w};
      float kk[4] = {k4.x, k4.y, k4.z, k4.w};
      #pragma unroll
      for (int p=0;p<4;++p){
        float tp = tv[p]*vv;
        #pragma unroll
        for (int jj=0;jj<4;++jj) acc[p][jj] += tp*kk[jj];
      }
    }
    #pragma unroll
    for (int p=0;p<4;++p){
      short4v h4, l4;
      #pragma unroll
      for (int jj=0;jj<4;++jj){ short a,bq; split2(acc[p][jj],a,bq); h4[jj]=a; l4[jj]=bq; }
      *(short4v*)(Bh + (p*32+m)*32 + jq*4) = h4;
      *(short4v*)(Bl + (p*32+m)*32 + jq*4) = l4;
    }
    if (t < 128){
      int p = t >> 5, j = t & 31;
      float s=0.f;
      const float* kp = kb + h*HDIM + j;
      for (int n=0;n<256;++n) s += t2[n*4+p]*kp[(b*NS+n)*CD];
      short a,bq; split2(s,a,bq);
      Bh[(128+p)*32 + j] = a;
      Bl[(128+p)*32 + j] = bq;
    } else {
      int idx = t - 128;       // zero pad rows 132..143 (384 shorts per plane)
      #pragma unroll
      for (int ii=0;ii<3;++ii){
        Bh[4224 + idx*3 + ii] = 0;
        Bl[4224 + idx*3 + ii] = 0;
      }
    }
  }
  __syncthreads();
  // ---- phase 2: attn GEMM (A = Q head planes, B = LDS planes) ----
  short8v bf_h[9], bf_l[9];
  #pragma unroll
  for (int nt=0; nt<9; ++nt){
    int row = nt*16 + r;
    bf_h[nt] = *(const short8v*)(Bh + row*32 + q*8);
    bf_l[nt] = *(const short8v*)(Bl + row*32 + q*8);
  }
  const short* qh_base = Qbh + ((size_t)h*65536 + (size_t)b*1024)*32;
  const short* ql_base = Qbl + ((size_t)h*65536 + (size_t)b*1024)*32;
  const f32x4 fz = {0.f,0.f,0.f,0.f};
  for (int u=0; u<4; ++u){
    __syncthreads();
    {
      const short8v* sh = (const short8v*)(qh_base + (u*256 + t)*32);
      const short8v* sl = (const short8v*)(ql_base + (u*256 + t)*32);
      short8v* dh = (short8v*)(Ah + t*32);
      short8v* dl = (short8v*)(Al + t*32);
      #pragma unroll
      for (int i=0;i<4;++i){ dh[i]=sh[i]; dl[i]=sl[i]; }
    }
    __syncthreads();
    #pragma unroll
    for (int mi=0; mi<4; ++mi){
      int mt = wave*4 + mi;
      short8v ah = *(const short8v*)(Ah + (mt*16 + r)*32 + q*8);
      short8v al = *(const short8v*)(Al + (mt*16 + r)*32 + q*8);
      f32x4 acc[9];
      #pragma unroll
      for (int nt=0;nt<9;++nt) acc[nt]=fz;
      #pragma unroll
      for (int nt=0;nt<9;++nt){
        acc[nt] = __builtin_amdgcn_mfma_f32_16x16x32_bf16(ah, bf_h[nt], acc[nt],0,0,0);
        acc[nt] = __builtin_amdgcn_mfma_f32_16x16x32_bf16(ah, bf_l[nt], acc[nt],0,0,0);
        acc[nt] = __builtin_amdgcn_mfma_f32_16x16x32_bf16(al, bf_h[nt], acc[nt],0,0,0);
      }
      int nbase = u*256 + mt*16 + q*4;
      int src = lane & 48;
      #pragma unroll
      for (int i=0;i<4;++i){
        int n = nbase + i;
        float4 tv = *(const float4*)(t1 + n*4);
        float dp0 = __shfl(acc[8][i], src+0, 64);
        float dp1 = __shfl(acc[8][i], src+1, 64);
        float dp2 = __shfl(acc[8][i], src+2, 64);
        float dp3 = __shfl(acc[8][i], src+3, 64);
        float den = tv.x*dp0 + tv.y*dp1 + tv.z*dp2 + tv.w*dp3;
        float a0 = tv.x*acc[0][i] + tv.y*acc[2][i] + tv.z*acc[4][i] + tv.w*acc[6][i];
        float a1 = tv.x*acc[1][i] + tv.y*acc[3][i] + tv.z*acc[5][i] + tv.w*acc[7][i];
        float sgn = (den>0.f) ? 1.f : ((den<0.f)? -1.f : 0.f);
        float ad = fminf(fmaxf(fabsf(den), 1e-4f), 1e4f);
        float inv = (den != 0.f) ? 1.0f/(ad*sgn) : 0.f;
        float o0 = a0*inv, o1 = a1*inv;
        int mrow = b*NTOK + n;
        short h0,l0,h1,l1;
        split2(o0,h0,l0); split2(o1,h1,l1);
        Ath[mrow*CD + h*HDIM + r]      = h0;
        Atl[mrow*CD + h*HDIM + r]      = l0;
        Ath[mrow*CD + h*HDIM + 16 + r] = h1;
        Atl[mrow*CD + h*HDIM + 16 + r] = l1;
      }
    }
  }
}

// ================= L4: out proj =================
__global__ __launch_bounds__(256) void k_outproj(const short* __restrict__ Ath, const short* __restrict__ Atl,
                                                 const short* __restrict__ Woh, const short* __restrict__ Wol,
                                                 const float* __restrict__ obv, const float* __restrict__ se,
                                                 float* __restrict__ dout){
  __shared__ __align__(16) short Ah[128*32];
  __shared__ __align__(16) short Al[128*32];
  __shared__ __align__(16) short Bh[128*32];
  __shared__ __align__(16) short Bl[128*32];
  int mblk = blockIdx.x >> 1, nblk = blockIdx.x & 1;
  int m0 = mblk*128, n0 = nblk*128;
  int t = threadIdx.x, wave = t>>6, lane = t&63;
  int wm = wave>>1, wn = wave&1;
  int q = lane>>4, r = lane&15;
  int cr = t>>2, cp = (t&3)*8;
  const f32x4 fz = {0.f,0.f,0.f,0.f};
  f32x4 acc[4][4];
  #pragma unroll
  for (int s=0;s<4;++s)
    #pragma unroll
    for (int tt=0;tt<4;++tt) acc[s][tt] = fz;
  for (int kc=0; kc<8; ++kc){
    int ko = kc*32;
    #pragma unroll
    for (int rep=0; rep<2; ++rep){
      int rr = cr + rep*64;
      int ga = (m0 + rr)*CD + ko + cp;
      *(short8v*)(Ah + rr*32 + cp) = *(const short8v*)(Ath + ga);
      *(short8v*)(Al + rr*32 + cp) = *(const short8v*)(Atl + ga);
      int gb = (n0 + rr)*CD + ko + cp;
      *(short8v*)(Bh + rr*32 + cp) = *(const short8v*)(Woh + gb);
      *(short8v*)(Bl + rr*32 + cp) = *(const short8v*)(Wol + gb);
    }
    __syncthreads();
    short8v ah[4], al[4];
    #pragma unroll
    for (int s=0;s<4;++s){
      int row = wm*64 + s*16 + r;
      ah[s] = *(const short8v*)(Ah + row*32 + q*8);
      al[s] = *(const short8v*)(Al + row*32 + q*8);
    }
    #pragma unroll
    for (int tt=0;tt<4;++tt){
      int brow = wn*64 + tt*16 + r;
      short8v bh = *(const short8v*)(Bh + brow*32 + q*8);
      short8v bl = *(const short8v*)(Bl + brow*32 + q*8);
      #pragma unroll
      for (int s=0;s<4;++s){
        acc[s][tt] = __builtin_amdgcn_mfma_f32_16x16x32_bf16(ah[s], bh, acc[s][tt], 0,0,0);
        acc[s][tt] = __builtin_amdgcn_mfma_f32_16x16x32_bf16(ah[s], bl, acc[s][tt], 0,0,0);
        acc[s][tt] = __builtin_amdgcn_mfma_f32_16x16x32_bf16(al[s], bh, acc[s][tt], 0,0,0);
      }
    }
    __syncthreads();
  }
  #pragma unroll
  for (int s=0;s<4;++s){
    #pragma unroll
    for (int tt=0;tt<4;++tt){
      int c = n0 + wn*64 + tt*16 + r;
      float bias = obv[c];
      #pragma unroll
      for (int i=0;i<4;++i){
        int m = m0 + wm*64 + s*16 + q*4 + i;
        int bb = m >> 10, ntok = m & 1023;
        float sev = se[bb*CD + c];
        dout[(ntok*NB + bb)*CD + c] = (acc[s][tt][i] + bias)*sev;
      }
    }
  }
}

extern "C" void kernel_launch(void* const* d_in, const int* in_sizes, int n_in,
                              void* d_out, int out_size, void* d_ws, size_t ws_size,
                              hipStream_t stream) {
  const float* query = (const float*)d_in[0];
  const float* ipw = (const float*)d_in[5];
  const float* ipb = (const float*)d_in[6];
  const float* srw = (const float*)d_in[7];
  const float* srb = (const float*)d_in[8];
  const float* ng  = (const float*)d_in[9];
  const float* nbb = (const float*)d_in[10];
  const float* ow  = (const float*)d_in[11];
  const float* obv = (const float*)d_in[12];
  const float* sw1 = (const float*)d_in[13];
  const float* sw2 = (const float*)d_in[14];
  float* dout = (float*)d_out;
  float* ws = (float*)d_ws;

  // ---- workspace layout (float offsets) ----
  short* Qbh  = (short*)ws;                // q head planes [h][m][32] [L1 qproj -> L3 attn]
  short* Qbl  = (short*)(ws + 8388608);
  float* R1   = ws + 16777216;             // multi-use region (16,777,216 f)
  float* kb   = R1;                        //  4,194,304 f  [L2 -> L3]
  float* vb   = R1 + 4194304;              //  4,194,304 f  [L2 -> L3]
  short* Ath  = (short*)(R1 + 8388608);    //  At hi plane [L3 -> L4] (no overlap with kb/vb)
  short* Atl  = (short*)(ws + 33554432);   //  At lo plane (over xr, dead after L2)
  float* xr   = ws + 33554432;             //  4,194,304 f  [L1 conv -> L2]   (overlaid by Atl in L3)
  float* part = ws + 44302336;             //     65,536 f  [L0 semean -> L1 semlp]
  float* se   = ws + 44367872;             //     16,384 f  [L1 semlp -> L4]
  float* t1   = ws + 44384256;             //      4,096 f
  float* t2   = ws + 44388352;             //      1,024 f
  short* Wih  = (short*)(ws + 44389376);   // 768x256
  short* Wil  = (short*)(ws + 44487680);
  short* Woh  = (short*)(ws + 44585984);   // 256x256
  short* Wol  = (short*)(ws + 44618752);
  short* Wsh  = (short*)(ws + 44651520);   // 256x1024
  short* Wsl  = (short*)(ws + 44782592);   // end: 44,913,664 f

  // L0: wcvt(256) | trig(4) | semean(256)
  k_pre   <<<516,  256,0,stream>>>(ipw, ow, srw, Wih, Wil, Woh, Wol, Wsh, Wsl, t1, t2, query, part);
  // L1: conv(512) | qproj(1024) | semlp(64)
  k_mid   <<<1600, 256,0,stream>>>(query, Wsh, Wsl, srb, xr, Wih, Wil, ipb, Qbh, Qbl, part, sw1, sw2, se);
  // L2: kvproj + fused layernorm (reads xr fp32)
  k_kvproj<<<512,  256,0,stream>>>(xr, ng, nbb, Wih + 256*CD, Wil + 256*CD, ipb, kb, vb);
  // L3: kv + attn fused (kv planes never leave LDS)
  k_kvattn<<<512,  256,0,stream>>>(kb, vb, t2, Qbh, Qbl, t1, Ath, Atl);
  // L4: out proj
  k_outproj<<<1024,256,0,stream>>>(Ath, Atl, Woh, Wol, obv, se, dout);
}